// Round 6
// baseline (356.736 us; speedup 1.0000x reference)
//
#include <hip/hip_runtime.h>
#include <stdint.h>

#define N_NODES 100000
#define N_EDGES 1600000
#define NBLK_SCAN 391   // ceil(N_NODES/256)

typedef __attribute__((ext_vector_type(8))) short short8;
typedef __attribute__((ext_vector_type(4))) float float4v;

__device__ __forceinline__ unsigned short f32_to_bf16(float f) {
  uint32_t u = __float_as_uint(f);
  u += 0x7fffu + ((u >> 16) & 1u);   // RNE
  return (unsigned short)(u >> 16);
}
__device__ __forceinline__ float bf16_to_f32(unsigned short h) {
  return __uint_as_float(((uint32_t)h) << 16);
}

// ---------------------------------------------------------------------------
// K_zero: deg=0, tilepack=0, tilectr=0; swizzle weight (tiles 0..49) and
// root_w (tiles 50..51) into MFMA B-fragment bf16 order.
// ---------------------------------------------------------------------------
__global__ __launch_bounds__(256) void k_zero(
    const float* __restrict__ weight, const float* __restrict__ root_w,
    int* __restrict__ deg, unsigned short* __restrict__ wbf,
    unsigned long long* __restrict__ tilepack, int* __restrict__ tilectr) {
  int tid = threadIdx.x;
  int b = blockIdx.x;
  int i = b * 256 + tid;
  if (i < N_NODES) deg[i] = 0;
  if (i < NBLK_SCAN) tilepack[i] = 0ull;
  if (i == 0) *tilectr = 0;
  if (b < 100) {            // 25600 weight elements
    int e = i;
    int km = e >> 10;
    int rem = e & 1023;
    int kk = rem >> 5;
    int fo = rem & 31;
    int t = km * 2 + (fo >> 4);
    int c = fo & 15;
    int q = kk >> 3, j = kk & 7;
    wbf[((t * 4 + q) * 16 + c) * 8 + j] = f32_to_bf16(weight[e]);
  } else if (b == 100) {    // 1024 root_w elements -> tiles 50,51
    for (int idx = tid; idx < 1024; idx += 256) {
      int kk = idx >> 5;
      int fo = idx & 31;
      int t = 50 + (fo >> 4);
      int c = fo & 15;
      int q = kk >> 3, j = kk & 7;
      wbf[((t * 4 + q) * 16 + c) * 8 + j] = f32_to_bf16(root_w[idx]);
    }
  }
}

// ---------------------------------------------------------------------------
// K1 (6250 blocks, 16 nodes each; 6250*256 == N_EDGES exactly):
//  - hist: rank[e] = atomicAdd(&deg[ei[e]],1)
//  - xw tile via MFMA 16x16x32 (tiles 0..49), LDS-staged, coalesced store
//  - tiles 50,51 = x@root_w: out = x_root+bias; r_dot = x_root.att_w[:32]
//  - ydot[n][k] = xw[n][k] . att_w[32:] (bf16) from the LDS tile
// ---------------------------------------------------------------------------
__global__ __launch_bounds__(256) void k1_xw(
    const float* __restrict__ x, const unsigned short* __restrict__ wbf,
    const int* __restrict__ ei, const float* __restrict__ att_w,
    const float* __restrict__ bias,
    int* __restrict__ deg, unsigned short* __restrict__ rank,
    unsigned short* __restrict__ xw, float* __restrict__ out,
    float* __restrict__ r_dot, unsigned short* __restrict__ ydot) {
  __shared__ __align__(16) unsigned short ot[16 * 808];
  __shared__ float xr[16][33];
  __shared__ float a2s[32];
  int tid = threadIdx.x;
  int b = blockIdx.x;

  int e = b * 256 + tid;
  int rk = atomicAdd(&deg[ei[e]], 1);

  if (tid < 32) a2s[tid] = att_w[32 + tid];

  int wave = tid >> 6, lane = tid & 63;
  int quad = lane >> 4, c16 = lane & 15;
  int n0 = b * 16;
  const float* xp = x + (size_t)(n0 + c16) * 32 + quad * 8;
  float4 a0 = *reinterpret_cast<const float4*>(xp);
  float4 a1 = *reinterpret_cast<const float4*>(xp + 4);
  short8 af;
  af[0] = (short)f32_to_bf16(a0.x); af[1] = (short)f32_to_bf16(a0.y);
  af[2] = (short)f32_to_bf16(a0.z); af[3] = (short)f32_to_bf16(a0.w);
  af[4] = (short)f32_to_bf16(a1.x); af[5] = (short)f32_to_bf16(a1.y);
  af[6] = (short)f32_to_bf16(a1.z); af[7] = (short)f32_to_bf16(a1.w);

  for (int t = wave; t < 52; t += 4) {
    short8 bf = *reinterpret_cast<const short8*>(wbf + ((t * 4 + quad) * 16 + c16) * 8);
    float4v acc = {0.f, 0.f, 0.f, 0.f};
    acc = __builtin_amdgcn_mfma_f32_16x16x32_bf16(af, bf, acc, 0, 0, 0);
    if (t < 50) {
      int cg = t * 16 + c16;
#pragma unroll
      for (int r = 0; r < 4; r++) ot[(quad * 4 + r) * 808 + cg] = f32_to_bf16(acc[r]);
    } else {
      int f = (t - 50) * 16 + c16;
#pragma unroll
      for (int r = 0; r < 4; r++) xr[quad * 4 + r][f] = acc[r];
    }
  }
  __syncthreads();

  // coalesced copy-out: ot rows (101 uint4 stride) -> xw rows (100 uint4)
  const uint4* src = (const uint4*)ot;
  uint4* dst = (uint4*)(xw + (size_t)n0 * 800);
  for (int i = tid; i < 1600; i += 256) {
    int r = i / 100;
    int c = i - r * 100;
    dst[r * 100 + c] = src[r * 101 + c];
  }
  // ydot (k-major lane assignment: idx = k*16 + n)
  for (int idx = tid; idx < 400; idx += 256) {
    int n = idx & 15;
    int k = idx >> 4;
    float s = 0.f;
#pragma unroll
    for (int ff = 0; ff < 32; ff++) s += bf16_to_f32(ot[n * 808 + k * 32 + ff]) * a2s[ff];
    ydot[(size_t)(n0 + n) * 25 + k] = f32_to_bf16(s);
  }
  // out = x_root + bias
  for (int idx = tid; idx < 512; idx += 256) {
    int n = idx >> 5, f = idx & 31;
    out[(n0 + n) * 32 + f] = xr[n][f] + bias[f];
  }
  // r_dot
  if (tid < 16) {
    float s = 0.f;
#pragma unroll
    for (int f = 0; f < 32; f++) s += xr[tid][f] * att_w[f];
    r_dot[n0 + tid] = s;
  }
  rank[e] = (unsigned short)rk;
}

// ---------------------------------------------------------------------------
// K_scan: single-kernel decoupled-lookback exclusive scan (391 tiles x 256).
// tilepack[t] = flag(hi32: 0=empty,1=aggregate,2=inclusive) | value(lo32).
// Wave-parallel lookback (64 tiles per step). Ticket order + all tiles
// co-resident (391 blocks) => no deadlock.
// ---------------------------------------------------------------------------
__global__ __launch_bounds__(256) void k_scan(
    const int* __restrict__ deg, int* __restrict__ offs,
    int* __restrict__ tilectr, unsigned long long* __restrict__ tilepack) {
  __shared__ int s[256];
  __shared__ int sh_tile, sh_excl;
  int tid = threadIdx.x;
  if (tid == 0) sh_tile = atomicAdd(tilectr, 1);
  __syncthreads();
  int tile = sh_tile;
  int i = tile * 256 + tid;
  int v = (i < N_NODES) ? deg[i] : 0;
  s[tid] = v;
  __syncthreads();
  for (int d = 1; d < 256; d <<= 1) {
    int t = (tid >= d) ? s[tid - d] : 0;
    __syncthreads();
    s[tid] += t;
    __syncthreads();
  }
  int incl = s[tid];
  int agg = s[255];
  if (tid == 0) {
    unsigned long long init = ((tile == 0) ? (2ull << 32) : (1ull << 32)) | (unsigned int)agg;
    __hip_atomic_store(&tilepack[tile], init, __ATOMIC_RELEASE, __HIP_MEMORY_SCOPE_AGENT);
    if (tile == 0) sh_excl = 0;
  }
  if (tile > 0 && tid < 64) {
    int excl = 0;
    int base = tile - 1;
    while (true) {
      int look = base - tid;
      unsigned long long pk;
      if (look >= 0) {
        do {
          pk = __hip_atomic_load(&tilepack[look], __ATOMIC_ACQUIRE, __HIP_MEMORY_SCOPE_AGENT);
        } while ((pk >> 32) == 0);
      } else {
        pk = (2ull << 32);   // virtual prefix 0 before tile 0
      }
      unsigned long long m2 = __ballot((pk >> 32) == 2);
      int lim = (m2 == 0ull) ? 64 : (__ffsll(m2) - 1);
      int val = (tid <= lim) ? (int)(unsigned int)pk : 0;
#pragma unroll
      for (int m = 1; m < 64; m <<= 1) val += __shfl_xor(val, m);
      excl += val;
      if (lim < 64) break;
      base -= 64;
    }
    if (tid == 0) {
      __hip_atomic_store(&tilepack[tile], (2ull << 32) | (unsigned int)(excl + agg),
                         __ATOMIC_RELEASE, __HIP_MEMORY_SCOPE_AGENT);
      sh_excl = excl;
    }
  }
  __syncthreads();
  if (i < N_NODES) offs[i] = sh_excl + incl - v;
  if (i == N_NODES - 1) offs[N_NODES] = N_EDGES;
}

// ---------------------------------------------------------------------------
// K_scatter: pos = offs[row] + rank[e] (no atomics). Computes the FULL
// attention weight here: alpha = rd[row] + sum_s b_s*ydot[col][w_s],
// ex = exp(leakyrelu(alpha)) -> packed into the 8B packet:
//   x: col(17) | i0(3) | i1(3) | fr0q(8) | spare(1)
//   y: fr1q(8) | spare(8) | ex_bf16(16, high bits)
// ---------------------------------------------------------------------------
__global__ __launch_bounds__(256) void kscatter(
    const int* __restrict__ ei, const float* __restrict__ pseudo,
    const int* __restrict__ offs, const unsigned short* __restrict__ rank,
    const float* __restrict__ r_dot, const unsigned short* __restrict__ ydot,
    uint2* __restrict__ epack) {
  int e = blockIdx.x * 256 + threadIdx.x;   // 6250 blocks: exact cover
  int r = ei[e];
  int c = ei[N_EDGES + e];
  int pos = offs[r] + (int)rank[e];
  float p0 = pseudo[2 * e] * 4.f;
  float p1 = pseudo[2 * e + 1] * 4.f;
  float fl0 = floorf(p0), fl1 = floorf(p1);
  float fr0 = p0 - fl0, fr1 = p1 - fl1;
  int i0 = (int)fl0, i1 = (int)fl1;
  int j0p = min(i0 + 1, 4);
  int j1 = 5 * i1, j1p = 5 * min(i1 + 1, 4);
  int rb = c * 25;
  float y0 = bf16_to_f32(ydot[rb + i0 + j1]);
  float y1 = bf16_to_f32(ydot[rb + j0p + j1]);
  float y2 = bf16_to_f32(ydot[rb + i0 + j1p]);
  float y3 = bf16_to_f32(ydot[rb + j0p + j1p]);
  float fm0 = 1.f - fr0, fm1 = 1.f - fr1;
  float b0 = fm0 * fm1, b1 = fr0 * fm1, b2 = fm0 * fr1, b3 = fr0 * fr1;
  float alpha = r_dot[r] + b0 * y0 + b1 * y1 + b2 * y2 + b3 * y3;
  alpha = fmaxf(alpha, 0.2f * alpha);   // leaky relu
  float ex = __expf(alpha);
  unsigned u = __float_as_uint(ex);
  unsigned exb = (u + 0x7fffu + ((u >> 16) & 1u)) & 0xffff0000u;  // bf16 RNE, kept high
  unsigned q0 = __float2uint_rn(fr0 * 255.f);
  unsigned q1 = __float2uint_rn(fr1 * 255.f);
  uint2 pk;
  pk.x = (unsigned)c | ((unsigned)i0 << 17) | ((unsigned)i1 << 20) | (q0 << 23);
  pk.y = exb | q1;
  epack[pos] = pk;
}

// ---------------------------------------------------------------------------
// K2: one wave per node; halves process alternate edges (lane=f_out).
// NO cross-lane ops, NO exp: just 4 gathers + blend + 2 fma per edge.
// 4-deep unroll per half for memory-level parallelism.
// ---------------------------------------------------------------------------
__device__ __forceinline__ void edge_step(uint2 pk, const unsigned short* __restrict__ xwf,
                                          float& acc, float& den) {
  int c  = (int)(pk.x & 0x1FFFF);
  int i0 = (int)((pk.x >> 17) & 7);
  int i1 = (int)((pk.x >> 20) & 7);
  float fr0 = (float)((pk.x >> 23) & 255u) * (1.f / 255.f);
  float fr1 = (float)(pk.y & 255u) * (1.f / 255.f);
  float ex = __uint_as_float(pk.y & 0xffff0000u);
  int j0p = min(i0 + 1, 4);
  int j1 = 5 * i1, j1p = 5 * min(i1 + 1, 4);
  int base = c * 800;
  float g0 = bf16_to_f32(xwf[base + (i0 + j1) * 32]);
  float g1 = bf16_to_f32(xwf[base + (j0p + j1) * 32]);
  float g2 = bf16_to_f32(xwf[base + (i0 + j1p) * 32]);
  float g3 = bf16_to_f32(xwf[base + (j0p + j1p) * 32]);
  float fm0 = 1.f - fr0, fm1 = 1.f - fr1;
  float msg = fm1 * (fm0 * g0 + fr0 * g1) + fr1 * (fm0 * g2 + fr0 * g3);
  acc = fmaf(msg, ex, acc);
  den += ex;
}

__global__ __launch_bounds__(256) void k2_csr(
    const int* __restrict__ offs, const uint2* __restrict__ epack,
    const unsigned short* __restrict__ xw, float* __restrict__ out) {
  int tid = threadIdx.x;
  int wave = tid >> 6, lane = tid & 63;
  int node = blockIdx.x * 4 + wave;
  if (node >= N_NODES) return;
  int f = lane & 31, half = lane >> 5;
  int s0 = offs[node], s1 = offs[node + 1];
  const unsigned short* xwf = xw + f;
  float acc = 0.f, den = 0.f;
  int i = s0 + half;

  for (; i + 6 < s1; i += 8) {
    uint2 p0 = epack[i];
    uint2 p1 = epack[i + 2];
    uint2 p2 = epack[i + 4];
    uint2 p3 = epack[i + 6];
    edge_step(p0, xwf, acc, den);
    edge_step(p1, xwf, acc, den);
    edge_step(p2, xwf, acc, den);
    edge_step(p3, xwf, acc, den);
  }
  for (; i < s1; i += 2) edge_step(epack[i], xwf, acc, den);

  acc += __shfl_xor(acc, 32);
  den += __shfl_xor(den, 32);
  if (half == 0) out[node * 32 + f] += acc / (den + 1e-16f);
}

extern "C" void kernel_launch(void* const* d_in, const int* in_sizes, int n_in,
                              void* d_out, int out_size, void* d_ws, size_t ws_size,
                              hipStream_t stream) {
  const float* x      = (const float*)d_in[0];
  const int*   ei     = (const int*)d_in[1];
  const float* pseudo = (const float*)d_in[2];
  const float* weight = (const float*)d_in[3];
  const float* root_w = (const float*)d_in[4];
  const float* att_w  = (const float*)d_in[5];
  const float* bias   = (const float*)d_in[6];
  float* out = (float*)d_out;

  char* ws = (char*)d_ws;
  unsigned short* xw   = (unsigned short*)ws;                 // 160,000,000 B
  float* r_dot         = (float*)(ws + 160000000);            //    400,000 B
  unsigned short* wbf  = (unsigned short*)(ws + 160400000);   //     53,248 B
  int* deg             = (int*)(ws + 160453248);              //    400,000 B
  int* offs            = (int*)(ws + 160853248);              //    400,016 B
  unsigned long long* tilepack = (unsigned long long*)(ws + 161253264); // 3,128 B
  int* tilectr         = (int*)(ws + 161256392);              //          8 B
  unsigned short* rank = (unsigned short*)(ws + 161256400);   //  3,200,000 B
  unsigned short* ydot = (unsigned short*)(ws + 164456400);   //  5,000,000 B
  uint2* epack         = (uint2*)(ws + 169456400);            // 12,800,000 B -> 182.3 MB

  hipLaunchKernelGGL(k_zero, dim3(NBLK_SCAN), dim3(256), 0, stream,
                     weight, root_w, deg, wbf, tilepack, tilectr);
  hipLaunchKernelGGL(k1_xw, dim3(6250), dim3(256), 0, stream,
                     x, wbf, ei, att_w, bias, deg, rank, xw, out, r_dot, ydot);
  hipLaunchKernelGGL(k_scan, dim3(NBLK_SCAN), dim3(256), 0, stream,
                     deg, offs, tilectr, tilepack);
  hipLaunchKernelGGL(kscatter, dim3(6250), dim3(256), 0, stream,
                     ei, pseudo, offs, rank, r_dot, ydot, epack);
  hipLaunchKernelGGL(k2_csr, dim3(25000), dim3(256), 0, stream,
                     offs, epack, xw, out);
}